// Round 1
// 1021.602 us; speedup vs baseline: 1.1627x; 1.1627x over previous
//
#include <hip/hip_runtime.h>
#include <math.h>

#define F 256

typedef __attribute__((ext_vector_type(8))) short short8;
typedef __attribute__((ext_vector_type(4))) float f32x4;
typedef __attribute__((ext_vector_type(2))) int i32x2;
typedef __attribute__((ext_vector_type(4))) unsigned short u16x4;
typedef __attribute__((ext_vector_type(8))) unsigned short u16x8;

__device__ __forceinline__ unsigned short f2bf(float f) {
  union { float f; unsigned u; } v; v.f = f;
  unsigned r = (v.u + 0x7fffu + ((v.u >> 16) & 1u)) >> 16;
  return (unsigned short)r;
}
__device__ __forceinline__ float bf2f(unsigned short h) {
  union { unsigned u; float f; } v; v.u = ((unsigned)h) << 16;
  return v.f;
}

// ---- prep: blocks [0,256): W[k][n] fp32 -> Wt[n][k] bf16.
//            blocks [256,..): x fp32 -> xb bf16 (8 elems/thread, NT reads).
__global__ void prep(const float* __restrict__ W, unsigned short* __restrict__ Wt,
                     const float* __restrict__ x, unsigned short* __restrict__ xb,
                     int NF, int do_xb) {
  if (blockIdx.x < 256) {
    int idx = blockIdx.x * 256 + threadIdx.x;
    int k = idx >> 8, n = idx & 255;
    Wt[n * F + k] = f2bf(W[k * F + n]);
    return;
  }
  if (!do_xb) return;
  int i0 = (blockIdx.x - 256) * 2048 + threadIdx.x * 8;
  if (i0 + 8 <= NF) {
    f32x4 a = __builtin_nontemporal_load((const f32x4*)(x + i0));
    f32x4 b = __builtin_nontemporal_load((const f32x4*)(x + i0 + 4));
    u16x8 o;
    o[0] = f2bf(a.x); o[1] = f2bf(a.y); o[2] = f2bf(a.z); o[3] = f2bf(a.w);
    o[4] = f2bf(b.x); o[5] = f2bf(b.y); o[6] = f2bf(b.z); o[7] = f2bf(b.w);
    *(u16x8*)(xb + i0) = o;
  } else {
    for (int i = i0; i < NF; ++i) xb[i] = f2bf(x[i]);
  }
}

// ---- CSR build: histogram ----
__global__ void hist_rows(const int* __restrict__ rows, int* counts, int E) {
  int e = blockIdx.x * 256 + threadIdx.x;
  if (e < E) atomicAdd(&counts[__builtin_nontemporal_load(&rows[e])], 1);
}

// ---- scan step 1: per-256 block local exclusive scan + block totals ----
__global__ void scan1(const int* __restrict__ counts, int* row_start, int* blk, int N) {
  __shared__ int tmp[256];
  int t = threadIdx.x;
  int i = blockIdx.x * 256 + t;
  int v = (i < N) ? counts[i] : 0;
  tmp[t] = v;
  __syncthreads();
#pragma unroll
  for (int off = 1; off < 256; off <<= 1) {
    int a = (t >= off) ? tmp[t - off] : 0;
    __syncthreads();
    tmp[t] += a;
    __syncthreads();
  }
  if (i < N) row_start[i] = tmp[t] - v;
  if (t == 255) blk[blockIdx.x] = tmp[255];
}

// ---- scan step 2: exclusive scan of block totals (NB <= 512), one block ----
__global__ void scan2(int* blk, int NB) {
  __shared__ int tmp[512];
  int t = threadIdx.x;
  int v = (t < NB) ? blk[t] : 0;
  tmp[t] = v;
  __syncthreads();
#pragma unroll
  for (int off = 1; off < 512; off <<= 1) {
    int a = (t >= off) ? tmp[t - off] : 0;
    __syncthreads();
    tmp[t] += a;
    __syncthreads();
  }
  if (t < NB) blk[t] = tmp[t] - v;
}

// ---- scan step 3: add block offsets; init fill ptrs; cap row_start[N] ----
__global__ void scan3(const int* __restrict__ counts, int* row_start,
                      const int* __restrict__ blk, int* fill_ptr, int N) {
  int i = blockIdx.x * 256 + threadIdx.x;
  if (i >= N) return;
  int rs = row_start[i] + blk[i >> 8];
  row_start[i] = rs;
  fill_ptr[i] = rs;
  if (i == N - 1) row_start[N] = rs + counts[i];
}

// ---- CSR fill: edges packed as (col, val_bits) ----
__global__ void fill_csr(const int* __restrict__ rows, const int* __restrict__ cols,
                         const float* __restrict__ vals, int* fill_ptr,
                         int2* __restrict__ edges, int E) {
  int e = blockIdx.x * 256 + threadIdx.x;
  if (e >= E) return;
  int r = __builtin_nontemporal_load(&rows[e]);
  int c = __builtin_nontemporal_load(&cols[e]);
  float v = __builtin_nontemporal_load(&vals[e]);
  int pos = atomicAdd(&fill_ptr[r], 1);
  edges[pos] = make_int2(c, __float_as_int(v));
}

// ---- gather (bf16 x): one wave per row, atomic-free, 4-deep ping-pong pipeline ----
__global__ __launch_bounds__(256) void gather_rows_bf16(
    const unsigned short* __restrict__ xb, const float* __restrict__ h0,
    const int* __restrict__ row_start, const i32x2* __restrict__ edges,
    float* __restrict__ support, const float* __restrict__ alpha_p, int N) {
  int gid = blockIdx.x * 256 + threadIdx.x;
  int r = gid >> 6;
  if (r >= N) return;
  int lane = threadIdx.x & 63;
  float alpha = *alpha_p;
  int s = row_start[r], e = row_start[r + 1];

  const unsigned short* xbl = xb + lane * 4;  // per-lane column base

  f32x4 acc0 = (f32x4){0.f, 0.f, 0.f, 0.f};
  f32x4 acc1 = (f32x4){0.f, 0.f, 0.f, 0.f};

  // Predicated single-edge load: beyond-end edges become (col=0, val=0, x=0).
#define LD1(ED, XV, jj)                                           \
  if ((jj) < e) {                                                 \
    ED = edges[jj];                                               \
    XV = *(const u16x4*)(xbl + (size_t)ED.x * F);                 \
  } else {                                                        \
    ED.x = 0; ED.y = 0;                                           \
    XV = (u16x4){0, 0, 0, 0};                                     \
  }

#define FMA1(ED, XV, ACC)                                         \
  {                                                               \
    float v = __int_as_float(ED.y);                               \
    ACC.x += v * bf2f(XV[0]);                                     \
    ACC.y += v * bf2f(XV[1]);                                     \
    ACC.z += v * bf2f(XV[2]);                                     \
    ACC.w += v * bf2f(XV[3]);                                     \
  }

  i32x2 eA0, eA1, eA2, eA3, eB0, eB1, eB2, eB3;
  u16x4 xA0, xA1, xA2, xA3, xB0, xB1, xB2, xB3;

  int j = s;
  LD1(eA0, xA0, j);
  LD1(eA1, xA1, j + 1);
  LD1(eA2, xA2, j + 2);
  LD1(eA3, xA3, j + 3);
  while (j < e) {
    int jn = j + 4;
    if (jn < e) {  // prefetch group B while group A computes
      LD1(eB0, xB0, jn);
      LD1(eB1, xB1, jn + 1);
      LD1(eB2, xB2, jn + 2);
      LD1(eB3, xB3, jn + 3);
    }
    FMA1(eA0, xA0, acc0);
    FMA1(eA1, xA1, acc1);
    FMA1(eA2, xA2, acc0);
    FMA1(eA3, xA3, acc1);
    j = jn;
    if (j >= e) break;
    jn = j + 4;
    if (jn < e) {  // prefetch group A while group B computes
      LD1(eA0, xA0, jn);
      LD1(eA1, xA1, jn + 1);
      LD1(eA2, xA2, jn + 2);
      LD1(eA3, xA3, jn + 3);
    }
    FMA1(eB0, xB0, acc0);
    FMA1(eB1, xB1, acc1);
    FMA1(eB2, xB2, acc0);
    FMA1(eB3, xB3, acc1);
    j = jn;
  }
#undef LD1
#undef FMA1

  f32x4 acc = acc0 + acc1;
  f32x4 b = __builtin_nontemporal_load((const f32x4*)(h0 + (size_t)r * F) + lane);
  float om = 1.0f - alpha;
  f32x4 o = om * acc + alpha * b;
  *((f32x4*)(support + (size_t)r * F) + lane) = o;
}

// ---- gather (fp32 x) fallback if ws can't hold xb ----
__global__ __launch_bounds__(256) void gather_rows_f32(
    const float* __restrict__ x, const float* __restrict__ h0,
    const int* __restrict__ row_start, const i32x2* __restrict__ edges,
    float* __restrict__ support, const float* __restrict__ alpha_p, int N) {
  int gid = blockIdx.x * 256 + threadIdx.x;
  int r = gid >> 6;
  if (r >= N) return;
  int lane = threadIdx.x & 63;
  float alpha = *alpha_p;
  int s = row_start[r], e = row_start[r + 1];
  f32x4 acc = (f32x4){0.f, 0.f, 0.f, 0.f};
  if (s < e) {
    i32x2 ed = __builtin_nontemporal_load(&edges[s]);
    f32x4 xv = *((const f32x4*)(x + (size_t)ed.x * F) + lane);
    for (int j = s; j < e; ++j) {
      i32x2 cur = ed;
      f32x4 xc = xv;
      if (j + 1 < e) {
        ed = __builtin_nontemporal_load(&edges[j + 1]);
        xv = *((const f32x4*)(x + (size_t)ed.x * F) + lane);
      }
      float v = __int_as_float(cur.y);
      acc += v * xc;
    }
  }
  f32x4 b = __builtin_nontemporal_load((const f32x4*)(h0 + (size_t)r * F) + lane);
  float om = 1.0f - alpha;
  f32x4 o = om * acc + alpha * b;
  *((f32x4*)(support + (size_t)r * F) + lane) = o;
}

// ---- GEMM + epilogue: out = theta*(support@W) + (1-theta)*support ----
// support and out alias (in-place): tile fully staged to LDS before writes.
__global__ __launch_bounds__(256) void gemm_epilogue(
    const float* support, const unsigned short* __restrict__ Wt, float* out,
    const float* __restrict__ lamda_p, const int* __restrict__ l_p, int N) {
  __shared__ unsigned short sup[64][264];  // +8 pad: 2-way bank alias (free)

  const float theta = logf(*lamda_p / (float)(*l_p) + 1.0f);
  const float one_m_t = 1.0f - theta;

  const int m0 = blockIdx.x * 64;
  const int t = threadIdx.x;

#pragma unroll
  for (int i = 0; i < 16; ++i) {
    int f = t + i * 256;
    int row = f >> 6, c4 = f & 63;
    int g_row = m0 + row;
    f32x4 a = (f32x4){0.f, 0.f, 0.f, 0.f};
    if (g_row < N)
      a = __builtin_nontemporal_load((const f32x4*)(support + (size_t)g_row * F) + c4);
    unsigned short* p = &sup[row][c4 << 2];
    p[0] = f2bf(a.x); p[1] = f2bf(a.y); p[2] = f2bf(a.z); p[3] = f2bf(a.w);
  }
  __syncthreads();

  const int wave = t >> 6, lane = t & 63;
  const int quad = lane >> 4, lcol = lane & 15;
  const int mrow = wave * 16;

  f32x4 acc[16];
#pragma unroll
  for (int n = 0; n < 16; ++n) acc[n] = (f32x4){0.f, 0.f, 0.f, 0.f};

#pragma unroll
  for (int k = 0; k < 8; ++k) {
    short8 afrag = *(const short8*)&sup[mrow + lcol][k * 32 + quad * 8];
#pragma unroll
    for (int n = 0; n < 16; ++n) {
      short8 bfrag = *(const short8*)&Wt[(size_t)(n * 16 + lcol) * F + k * 32 + quad * 8];
      acc[n] = __builtin_amdgcn_mfma_f32_16x16x32_bf16(afrag, bfrag, acc[n], 0, 0, 0);
    }
  }

#pragma unroll
  for (int n = 0; n < 16; ++n) {
#pragma unroll
    for (int r = 0; r < 4; ++r) {
      int lrow = mrow + quad * 4 + r;
      int col = n * 16 + lcol;
      int g_row = m0 + lrow;
      if (g_row < N) {
        float s = bf2f(sup[lrow][col]);
        __builtin_nontemporal_store(theta * acc[n][r] + one_m_t * s,
                                    &out[(size_t)g_row * F + col]);
      }
    }
  }
}

extern "C" void kernel_launch(void* const* d_in, const int* in_sizes, int n_in,
                              void* d_out, int out_size, void* d_ws, size_t ws_size,
                              hipStream_t stream) {
  const float* x     = (const float*)d_in[0];
  const int*   rows  = (const int*)d_in[1];
  const int*   cols  = (const int*)d_in[2];
  const float* vals  = (const float*)d_in[3];
  const float* h0    = (const float*)d_in[4];
  const float* W     = (const float*)d_in[5];
  const float* lamda = (const float*)d_in[6];
  const float* alpha = (const float*)d_in[7];
  const int*   lp    = (const int*)d_in[8];

  const int E = in_sizes[1];
  const int N = in_sizes[0] / F;
  const int NF = N * F;

  // ---- workspace layout (256B aligned regions) ----
  size_t off = 0;
  auto take = [&](size_t bytes) { size_t o = off; off += (bytes + 255) & ~(size_t)255; return o; };
  char* ws = (char*)d_ws;
  unsigned short* Wt  = (unsigned short*)(ws + take((size_t)F * F * 2));
  int* counts    = (int*)(ws + take((size_t)N * 4));
  int* row_start = (int*)(ws + take((size_t)(N + 1) * 4));
  int* fill_ptr  = (int*)(ws + take((size_t)N * 4));
  int* blk       = (int*)(ws + take(4096));
  i32x2* edges   = (i32x2*)(ws + take((size_t)E * 8));
  size_t need_base = off;
  unsigned short* xb = (unsigned short*)(ws + take((size_t)NF * 2));
  const int use_bf16 = (off <= ws_size) && ((need_base) <= ws_size);

  float* out = (float*)d_out;

  hipMemsetAsync(counts, 0, (size_t)N * sizeof(int), stream);

  int nxb = use_bf16 ? (NF + 2047) / 2048 : 0;
  prep<<<256 + nxb, 256, 0, stream>>>(W, Wt, x, xb, NF, use_bf16);

  int eb = (E + 255) / 256;
  int nb = (N + 255) / 256;  // must be <= 512 for scan2 (N=100000 -> 391)

  hist_rows<<<eb, 256, 0, stream>>>(rows, counts, E);
  scan1<<<nb, 256, 0, stream>>>(counts, row_start, blk, N);
  scan2<<<1, 512, 0, stream>>>(blk, nb);
  scan3<<<nb, 256, 0, stream>>>(counts, row_start, blk, fill_ptr, N);
  fill_csr<<<eb, 256, 0, stream>>>(rows, cols, vals, fill_ptr, (int2*)edges, E);

  int gather_blocks = (N * 64 + 255) / 256;
  if (use_bf16) {
    gather_rows_bf16<<<gather_blocks, 256, 0, stream>>>(xb, h0, row_start, edges,
                                                        out, alpha, N);
  } else {
    gather_rows_f32<<<gather_blocks, 256, 0, stream>>>(x, h0, row_start, edges,
                                                       out, alpha, N);
  }

  gemm_epilogue<<<(N + 63) / 64, 256, 0, stream>>>(out, Wt, out, lamda, lp, N);
}

// Round 2
// 984.012 us; speedup vs baseline: 1.2071x; 1.0382x over previous
//
#include <hip/hip_runtime.h>
#include <math.h>

#define F 256

typedef __attribute__((ext_vector_type(8))) short short8;
typedef __attribute__((ext_vector_type(4))) float f32x4;
typedef __attribute__((ext_vector_type(2))) int i32x2;
typedef __attribute__((ext_vector_type(4))) unsigned short u16x4;
typedef __attribute__((ext_vector_type(8))) unsigned short u16x8;

__device__ __forceinline__ unsigned short f2bf(float f) {
  union { float f; unsigned u; } v; v.f = f;
  unsigned r = (v.u + 0x7fffu + ((v.u >> 16) & 1u)) >> 16;
  return (unsigned short)r;
}
__device__ __forceinline__ float bf2f(unsigned short h) {
  union { unsigned u; float f; } v; v.u = ((unsigned)h) << 16;
  return v.f;
}

// ---- prep: blocks [0,256): W[k][n] fp32 -> Wt[n][k] bf16.
//            blocks [256,..): x fp32 -> xb bf16 (8 elems/thread, NT reads).
__global__ void prep(const float* __restrict__ W, unsigned short* __restrict__ Wt,
                     const float* __restrict__ x, unsigned short* __restrict__ xb,
                     int NF, int do_xb) {
  if (blockIdx.x < 256) {
    int idx = blockIdx.x * 256 + threadIdx.x;
    int k = idx >> 8, n = idx & 255;
    Wt[n * F + k] = f2bf(W[k * F + n]);
    return;
  }
  if (!do_xb) return;
  int i0 = (blockIdx.x - 256) * 2048 + threadIdx.x * 8;
  if (i0 + 8 <= NF) {
    f32x4 a = __builtin_nontemporal_load((const f32x4*)(x + i0));
    f32x4 b = __builtin_nontemporal_load((const f32x4*)(x + i0 + 4));
    u16x8 o;
    o[0] = f2bf(a.x); o[1] = f2bf(a.y); o[2] = f2bf(a.z); o[3] = f2bf(a.w);
    o[4] = f2bf(b.x); o[5] = f2bf(b.y); o[6] = f2bf(b.z); o[7] = f2bf(b.w);
    *(u16x8*)(xb + i0) = o;
  } else {
    for (int i = i0; i < NF; ++i) xb[i] = f2bf(x[i]);
  }
}

// ---- CSR build: histogram ----
__global__ void hist_rows(const int* __restrict__ rows, int* counts, int E) {
  int e = blockIdx.x * 256 + threadIdx.x;
  if (e < E) atomicAdd(&counts[__builtin_nontemporal_load(&rows[e])], 1);
}

// ---- scan step 1: per-256 block local exclusive scan + block totals ----
__global__ void scan1(const int* __restrict__ counts, int* row_start, int* blk, int N) {
  __shared__ int tmp[256];
  int t = threadIdx.x;
  int i = blockIdx.x * 256 + t;
  int v = (i < N) ? counts[i] : 0;
  tmp[t] = v;
  __syncthreads();
#pragma unroll
  for (int off = 1; off < 256; off <<= 1) {
    int a = (t >= off) ? tmp[t - off] : 0;
    __syncthreads();
    tmp[t] += a;
    __syncthreads();
  }
  if (i < N) row_start[i] = tmp[t] - v;
  if (t == 255) blk[blockIdx.x] = tmp[255];
}

// ---- scan step 2: exclusive scan of block totals (NB <= 512), one block ----
__global__ void scan2(int* blk, int NB) {
  __shared__ int tmp[512];
  int t = threadIdx.x;
  int v = (t < NB) ? blk[t] : 0;
  tmp[t] = v;
  __syncthreads();
#pragma unroll
  for (int off = 1; off < 512; off <<= 1) {
    int a = (t >= off) ? tmp[t - off] : 0;
    __syncthreads();
    tmp[t] += a;
    __syncthreads();
  }
  if (t < NB) blk[t] = tmp[t] - v;
}

// ---- scan step 3: add block offsets; init fill ptrs; cap row_start[N] ----
__global__ void scan3(const int* __restrict__ counts, int* row_start,
                      const int* __restrict__ blk, int* fill_ptr, int N) {
  int i = blockIdx.x * 256 + threadIdx.x;
  if (i >= N) return;
  int rs = row_start[i] + blk[i >> 8];
  row_start[i] = rs;
  fill_ptr[i] = rs;
  if (i == N - 1) row_start[N] = rs + counts[i];
}

// ---- CSR fill: edges packed as (col, val_bits) ----
__global__ void fill_csr(const int* __restrict__ rows, const int* __restrict__ cols,
                         const float* __restrict__ vals, int* fill_ptr,
                         int2* __restrict__ edges, int E) {
  int e = blockIdx.x * 256 + threadIdx.x;
  if (e >= E) return;
  int r = __builtin_nontemporal_load(&rows[e]);
  int c = __builtin_nontemporal_load(&cols[e]);
  float v = __builtin_nontemporal_load(&vals[e]);
  int pos = atomicAdd(&fill_ptr[r], 1);
  edges[pos] = make_int2(c, __float_as_int(v));
}

// ---- gather (bf16 x): one wave per row. Wave-wide bulk edge load (64 edges
//      at once), readlane broadcast of (col,val) -> all x-row addresses known
//      upfront (no edge->x dependent chain). x-loads pipelined 8-deep ping-pong
//      (up to 16 in flight). val lives in SGPRs.
__global__ __launch_bounds__(256) void gather_rows_bf16(
    const unsigned short* __restrict__ xb, const float* __restrict__ h0,
    const int* __restrict__ row_start, const i32x2* __restrict__ edges,
    float* __restrict__ support, const float* __restrict__ alpha_p, int N) {
  int gid = blockIdx.x * 256 + threadIdx.x;
  int r = gid >> 6;
  if (r >= N) return;
  int lane = threadIdx.x & 63;
  float alpha = *alpha_p;
  int s = row_start[r], e = row_start[r + 1];

  const unsigned short* xbl = xb + lane * 4;  // per-lane column base

  f32x4 acc0 = (f32x4){0.f, 0.f, 0.f, 0.f};
  f32x4 acc1 = (f32x4){0.f, 0.f, 0.f, 0.f};

  // Load 8 x-rows for edges [JB, JB+8) of the current chunk.
  // Edge (col,val) broadcast from lane JB+k via readlane (uniform index).
  // Lanes >= cnt hold (col=0, val=0) -> contribute exactly 0.
#define GRP_LOAD(XV, VV, JB)                                             \
  {                                                                      \
    _Pragma("unroll")                                                    \
    for (int k = 0; k < 8; ++k) {                                        \
      int col = __builtin_amdgcn_readlane(med.x, (JB) + k);              \
      VV[k] = __int_as_float(__builtin_amdgcn_readlane(med.y, (JB) + k)); \
      XV[k] = *(const u16x4*)(xbl + (size_t)col * F);                    \
    }                                                                    \
  }

#define GRP_FMA(XV, VV)                                                  \
  {                                                                      \
    _Pragma("unroll")                                                    \
    for (int k = 0; k < 8; ++k) {                                        \
      f32x4& A = (k & 1) ? acc1 : acc0;                                  \
      A.x += VV[k] * bf2f(XV[k][0]);                                     \
      A.y += VV[k] * bf2f(XV[k][1]);                                     \
      A.z += VV[k] * bf2f(XV[k][2]);                                     \
      A.w += VV[k] * bf2f(XV[k][3]);                                     \
    }                                                                    \
  }

  while (s < e) {
    int cnt = e - s;
    if (cnt > 64) cnt = 64;

    i32x2 med;
    if (lane < cnt) {
      med = edges[s + lane];
    } else {
      med.x = 0; med.y = 0;
    }

    u16x4 xA[8], xB[8];
    float vA[8], vB[8];

    int jb = 0;
    GRP_LOAD(xA, vA, 0);
    while (true) {
      int jn = jb + 8;
      if (jn < cnt) GRP_LOAD(xB, vB, jn);
      GRP_FMA(xA, vA);
      jb = jn;
      if (jb >= cnt) break;
      jn = jb + 8;
      if (jn < cnt) GRP_LOAD(xA, vA, jn);
      GRP_FMA(xB, vB);
      jb = jn;
      if (jb >= cnt) break;
    }
    s += cnt;
  }
#undef GRP_LOAD
#undef GRP_FMA

  f32x4 acc = acc0 + acc1;
  f32x4 b = __builtin_nontemporal_load((const f32x4*)(h0 + (size_t)r * F) + lane);
  float om = 1.0f - alpha;
  f32x4 o = om * acc + alpha * b;
  *((f32x4*)(support + (size_t)r * F) + lane) = o;
}

// ---- gather (fp32 x) fallback if ws can't hold xb ----
__global__ __launch_bounds__(256) void gather_rows_f32(
    const float* __restrict__ x, const float* __restrict__ h0,
    const int* __restrict__ row_start, const i32x2* __restrict__ edges,
    float* __restrict__ support, const float* __restrict__ alpha_p, int N) {
  int gid = blockIdx.x * 256 + threadIdx.x;
  int r = gid >> 6;
  if (r >= N) return;
  int lane = threadIdx.x & 63;
  float alpha = *alpha_p;
  int s = row_start[r], e = row_start[r + 1];
  f32x4 acc = (f32x4){0.f, 0.f, 0.f, 0.f};
  if (s < e) {
    i32x2 ed = __builtin_nontemporal_load(&edges[s]);
    f32x4 xv = *((const f32x4*)(x + (size_t)ed.x * F) + lane);
    for (int j = s; j < e; ++j) {
      i32x2 cur = ed;
      f32x4 xc = xv;
      if (j + 1 < e) {
        ed = __builtin_nontemporal_load(&edges[j + 1]);
        xv = *((const f32x4*)(x + (size_t)ed.x * F) + lane);
      }
      float v = __int_as_float(cur.y);
      acc += v * xc;
    }
  }
  f32x4 b = __builtin_nontemporal_load((const f32x4*)(h0 + (size_t)r * F) + lane);
  float om = 1.0f - alpha;
  f32x4 o = om * acc + alpha * b;
  *((f32x4*)(support + (size_t)r * F) + lane) = o;
}

// ---- GEMM + epilogue: out = theta*(support@W) + (1-theta)*support ----
// support and out alias (in-place): tile fully staged to LDS before writes.
__global__ __launch_bounds__(256) void gemm_epilogue(
    const float* support, const unsigned short* __restrict__ Wt, float* out,
    const float* __restrict__ lamda_p, const int* __restrict__ l_p, int N) {
  __shared__ unsigned short sup[64][264];  // +8 pad: 2-way bank alias (free)

  const float theta = logf(*lamda_p / (float)(*l_p) + 1.0f);
  const float one_m_t = 1.0f - theta;

  const int m0 = blockIdx.x * 64;
  const int t = threadIdx.x;

#pragma unroll
  for (int i = 0; i < 16; ++i) {
    int f = t + i * 256;
    int row = f >> 6, c4 = f & 63;
    int g_row = m0 + row;
    f32x4 a = (f32x4){0.f, 0.f, 0.f, 0.f};
    if (g_row < N)
      a = __builtin_nontemporal_load((const f32x4*)(support + (size_t)g_row * F) + c4);
    unsigned short* p = &sup[row][c4 << 2];
    p[0] = f2bf(a.x); p[1] = f2bf(a.y); p[2] = f2bf(a.z); p[3] = f2bf(a.w);
  }
  __syncthreads();

  const int wave = t >> 6, lane = t & 63;
  const int quad = lane >> 4, lcol = lane & 15;
  const int mrow = wave * 16;

  f32x4 acc[16];
#pragma unroll
  for (int n = 0; n < 16; ++n) acc[n] = (f32x4){0.f, 0.f, 0.f, 0.f};

#pragma unroll
  for (int k = 0; k < 8; ++k) {
    short8 afrag = *(const short8*)&sup[mrow + lcol][k * 32 + quad * 8];
#pragma unroll
    for (int n = 0; n < 16; ++n) {
      short8 bfrag = *(const short8*)&Wt[(size_t)(n * 16 + lcol) * F + k * 32 + quad * 8];
      acc[n] = __builtin_amdgcn_mfma_f32_16x16x32_bf16(afrag, bfrag, acc[n], 0, 0, 0);
    }
  }

#pragma unroll
  for (int n = 0; n < 16; ++n) {
#pragma unroll
    for (int r = 0; r < 4; ++r) {
      int lrow = mrow + quad * 4 + r;
      int col = n * 16 + lcol;
      int g_row = m0 + lrow;
      if (g_row < N) {
        float s = bf2f(sup[lrow][col]);
        __builtin_nontemporal_store(theta * acc[n][r] + one_m_t * s,
                                    &out[(size_t)g_row * F + col]);
      }
    }
  }
}

extern "C" void kernel_launch(void* const* d_in, const int* in_sizes, int n_in,
                              void* d_out, int out_size, void* d_ws, size_t ws_size,
                              hipStream_t stream) {
  const float* x     = (const float*)d_in[0];
  const int*   rows  = (const int*)d_in[1];
  const int*   cols  = (const int*)d_in[2];
  const float* vals  = (const float*)d_in[3];
  const float* h0    = (const float*)d_in[4];
  const float* W     = (const float*)d_in[5];
  const float* lamda = (const float*)d_in[6];
  const float* alpha = (const float*)d_in[7];
  const int*   lp    = (const int*)d_in[8];

  const int E = in_sizes[1];
  const int N = in_sizes[0] / F;
  const int NF = N * F;

  // ---- workspace layout (256B aligned regions) ----
  size_t off = 0;
  auto take = [&](size_t bytes) { size_t o = off; off += (bytes + 255) & ~(size_t)255; return o; };
  char* ws = (char*)d_ws;
  unsigned short* Wt  = (unsigned short*)(ws + take((size_t)F * F * 2));
  int* counts    = (int*)(ws + take((size_t)N * 4));
  int* row_start = (int*)(ws + take((size_t)(N + 1) * 4));
  int* fill_ptr  = (int*)(ws + take((size_t)N * 4));
  int* blk       = (int*)(ws + take(4096));
  i32x2* edges   = (i32x2*)(ws + take((size_t)E * 8));
  size_t need_base = off;
  unsigned short* xb = (unsigned short*)(ws + take((size_t)NF * 2));
  const int use_bf16 = (off <= ws_size) && ((need_base) <= ws_size);

  float* out = (float*)d_out;

  hipMemsetAsync(counts, 0, (size_t)N * sizeof(int), stream);

  int nxb = use_bf16 ? (NF + 2047) / 2048 : 0;
  prep<<<256 + nxb, 256, 0, stream>>>(W, Wt, x, xb, NF, use_bf16);

  int eb = (E + 255) / 256;
  int nb = (N + 255) / 256;  // must be <= 512 for scan2 (N=100000 -> 391)

  hist_rows<<<eb, 256, 0, stream>>>(rows, counts, E);
  scan1<<<nb, 256, 0, stream>>>(counts, row_start, blk, N);
  scan2<<<1, 512, 0, stream>>>(blk, nb);
  scan3<<<nb, 256, 0, stream>>>(counts, row_start, blk, fill_ptr, N);
  fill_csr<<<eb, 256, 0, stream>>>(rows, cols, vals, fill_ptr, (int2*)edges, E);

  int gather_blocks = (N * 64 + 255) / 256;
  if (use_bf16) {
    gather_rows_bf16<<<gather_blocks, 256, 0, stream>>>(xb, h0, row_start, edges,
                                                        out, alpha, N);
  } else {
    gather_rows_f32<<<gather_blocks, 256, 0, stream>>>(x, h0, row_start, edges,
                                                       out, alpha, N);
  }

  gemm_epilogue<<<(N + 63) / 64, 256, 0, stream>>>(out, Wt, out, lamda, lp, N);
}

// Round 3
// 832.975 us; speedup vs baseline: 1.4260x; 1.1813x over previous
//
#include <hip/hip_runtime.h>
#include <math.h>

#define F 256

#define BKT_SHIFT 7
#define BKT_ROWS 128
#define BKT_CAP 8192   // LDS-sorted bucket capacity (64 KB)
#define NB_MAX 1024
#define BIN_CHUNK 8192

typedef __attribute__((ext_vector_type(8))) short short8;
typedef __attribute__((ext_vector_type(4))) float f32x4;
typedef __attribute__((ext_vector_type(2))) int i32x2;
typedef __attribute__((ext_vector_type(4))) unsigned short u16x4;
typedef __attribute__((ext_vector_type(8))) unsigned short u16x8;

__device__ __forceinline__ unsigned short f2bf(float f) {
  union { float f; unsigned u; } v; v.f = f;
  unsigned r = (v.u + 0x7fffu + ((v.u >> 16) & 1u)) >> 16;
  return (unsigned short)r;
}
__device__ __forceinline__ float bf2f(unsigned short h) {
  union { unsigned u; float f; } v; v.u = ((unsigned)h) << 16;
  return v.f;
}

// ---- prep: blocks [0,256): W[k][n] fp32 -> Wt[n][k] bf16.
//            blocks [256,..): x fp32 -> xb bf16 (8 elems/thread, NT reads).
__global__ void prep(const float* __restrict__ W, unsigned short* __restrict__ Wt,
                     const float* __restrict__ x, unsigned short* __restrict__ xb,
                     int NF, int do_xb) {
  if (blockIdx.x < 256) {
    int idx = blockIdx.x * 256 + threadIdx.x;
    int k = idx >> 8, n = idx & 255;
    Wt[n * F + k] = f2bf(W[k * F + n]);
    return;
  }
  if (!do_xb) return;
  int i0 = (blockIdx.x - 256) * 2048 + threadIdx.x * 8;
  if (i0 + 8 <= NF) {
    f32x4 a = __builtin_nontemporal_load((const f32x4*)(x + i0));
    f32x4 b = __builtin_nontemporal_load((const f32x4*)(x + i0 + 4));
    u16x8 o;
    o[0] = f2bf(a.x); o[1] = f2bf(a.y); o[2] = f2bf(a.z); o[3] = f2bf(a.w);
    o[4] = f2bf(b.x); o[5] = f2bf(b.y); o[6] = f2bf(b.z); o[7] = f2bf(b.w);
    *(u16x8*)(xb + i0) = o;
  } else {
    for (int i = i0; i < NF; ++i) xb[i] = f2bf(x[i]);
  }
}

// ---- CSR build: histogram ----
__global__ void hist_rows(const int* __restrict__ rows, int* counts, int E) {
  int e = blockIdx.x * 256 + threadIdx.x;
  if (e < E) atomicAdd(&counts[__builtin_nontemporal_load(&rows[e])], 1);
}

// ---- scan step 1: per-256 block local exclusive scan + block totals ----
__global__ void scan1(const int* __restrict__ counts, int* row_start, int* blk, int N) {
  __shared__ int tmp[256];
  int t = threadIdx.x;
  int i = blockIdx.x * 256 + t;
  int v = (i < N) ? counts[i] : 0;
  tmp[t] = v;
  __syncthreads();
#pragma unroll
  for (int off = 1; off < 256; off <<= 1) {
    int a = (t >= off) ? tmp[t - off] : 0;
    __syncthreads();
    tmp[t] += a;
    __syncthreads();
  }
  if (i < N) row_start[i] = tmp[t] - v;
  if (t == 255) blk[blockIdx.x] = tmp[255];
}

// ---- scan step 2: exclusive scan of block totals (NB <= 512), one block ----
__global__ void scan2(int* blk, int NB) {
  __shared__ int tmp[512];
  int t = threadIdx.x;
  int v = (t < NB) ? blk[t] : 0;
  tmp[t] = v;
  __syncthreads();
#pragma unroll
  for (int off = 1; off < 512; off <<= 1) {
    int a = (t >= off) ? tmp[t - off] : 0;
    __syncthreads();
    tmp[t] += a;
    __syncthreads();
  }
  if (t < NB) blk[t] = tmp[t] - v;
}

// ---- scan step 3: add block offsets; init fill ptrs + bucket cursors ----
__global__ void scan3(const int* __restrict__ counts, int* row_start,
                      const int* __restrict__ blk, int* fill_ptr, int* bcur, int N) {
  int i = blockIdx.x * 256 + threadIdx.x;
  if (i >= N) return;
  int rs = row_start[i] + blk[i >> 8];
  row_start[i] = rs;
  fill_ptr[i] = rs;
  if ((i & (BKT_ROWS - 1)) == 0) bcur[i >> BKT_SHIFT] = rs;
  if (i == N - 1) row_start[N] = rs + counts[i];
}

// ---- CSR fill (fallback path only): edges packed as (col, val_bits) ----
__global__ void fill_csr(const int* __restrict__ rows, const int* __restrict__ cols,
                         const float* __restrict__ vals, int* fill_ptr,
                         int2* __restrict__ edges, int E) {
  int e = blockIdx.x * 256 + threadIdx.x;
  if (e >= E) return;
  int r = __builtin_nontemporal_load(&rows[e]);
  int c = __builtin_nontemporal_load(&cols[e]);
  float v = __builtin_nontemporal_load(&vals[e]);
  int pos = atomicAdd(&fill_ptr[r], 1);
  edges[pos] = make_int2(c, __float_as_int(v));
}

// ---- bin pass A: block-aggregated binning into 128-row buckets.
// One global atomic per (block,bucket); writes land in dense per-bucket runs
// (~10 edges) so L2 assembles mostly-full lines. Packs (col | row_local<<20).
__global__ __launch_bounds__(512) void bin_edges(
    const int* __restrict__ rows, const int* __restrict__ cols,
    const float* __restrict__ vals, int* __restrict__ bcur,
    i32x2* __restrict__ etmp, int E, int NB) {
  __shared__ unsigned hist[NB_MAX];
  __shared__ unsigned base[NB_MAX];
  const int tid = threadIdx.x;
  const int e0 = blockIdx.x * BIN_CHUNK;

  for (int b = tid; b < NB; b += 512) hist[b] = 0;
  __syncthreads();
#pragma unroll
  for (int k = 0; k < BIN_CHUNK / 512; ++k) {
    int e = e0 + k * 512 + tid;
    if (e < E) {
      unsigned b = (unsigned)__builtin_nontemporal_load(&rows[e]) >> BKT_SHIFT;
      atomicAdd(&hist[b], 1u);
    }
  }
  __syncthreads();
  for (int b = tid; b < NB; b += 512) {
    unsigned c = hist[b];
    base[b] = c ? (unsigned)atomicAdd(&bcur[b], (int)c) : 0u;
    hist[b] = 0;
  }
  __syncthreads();
#pragma unroll
  for (int k = 0; k < BIN_CHUNK / 512; ++k) {
    int e = e0 + k * 512 + tid;
    if (e < E) {
      int r = rows[e];
      unsigned b = (unsigned)r >> BKT_SHIFT;
      unsigned idx = atomicAdd(&hist[b], 1u);
      int pos = (int)(base[b] + idx);
      int c = cols[e];
      float v = vals[e];
      etmp[pos] = (i32x2){c | ((r & (BKT_ROWS - 1)) << 20), __float_as_int(v)};
    }
  }
}

// ---- bin pass B: per-bucket CSR finish. LDS hist -> scan -> stable LDS
// scatter -> coalesced write of the final CSR segment. Strips row bits.
__global__ __launch_bounds__(512) void sort_bucket(
    const i32x2* __restrict__ etmp, const int* __restrict__ row_start,
    int* __restrict__ fill_ptr, i32x2* __restrict__ edges, int N) {
  __shared__ int cur[BKT_ROWS];
  __shared__ i32x2 sorted[BKT_CAP];
  const int b = blockIdx.x;
  const int r0 = b << BKT_SHIFT;
  int rend = r0 + BKT_ROWS; if (rend > N) rend = N;
  const int seg0 = row_start[r0];
  const int seg1 = row_start[rend];
  const int cnt = seg1 - seg0;
  const int tid = threadIdx.x;

  if (cnt <= BKT_CAP) {
    if (tid < BKT_ROWS) cur[tid] = 0;
    __syncthreads();
    for (int i = tid; i < cnt; i += 512) {
      i32x2 w = etmp[seg0 + i];
      atomicAdd(&cur[(w.x >> 20) & (BKT_ROWS - 1)], 1);
    }
    __syncthreads();
    int myc = (tid < BKT_ROWS) ? cur[tid] : 0;
    __syncthreads();
    // Hillis-Steele inclusive scan over 128 counters
    for (int off = 1; off < BKT_ROWS; off <<= 1) {
      int a = 0;
      if (tid < BKT_ROWS && tid >= off) a = cur[tid - off];
      __syncthreads();
      if (tid < BKT_ROWS) cur[tid] += a;
      __syncthreads();
    }
    if (tid < BKT_ROWS) cur[tid] -= myc;  // exclusive prefix = running cursor
    __syncthreads();
    for (int i = tid; i < cnt; i += 512) {
      i32x2 w = etmp[seg0 + i];
      int rl = (w.x >> 20) & (BKT_ROWS - 1);
      int idx = atomicAdd(&cur[rl], 1);
      sorted[idx] = (i32x2){w.x & 0xFFFFF, w.y};
    }
    __syncthreads();
    for (int i = tid; i < cnt; i += 512)
      edges[seg0 + i] = sorted[i];
  } else {
    // statistically-unreachable overflow fallback: global-atomic fill
    for (int i = tid; i < cnt; i += 512) {
      i32x2 w = etmp[seg0 + i];
      int r = r0 + ((w.x >> 20) & (BKT_ROWS - 1));
      int pos = atomicAdd(&fill_ptr[r], 1);
      edges[pos] = (i32x2){w.x & 0xFFFFF, w.y};
    }
  }
}

// ---- gather (bf16 x): one wave per row. Wave-wide bulk edge load (64 edges
//      at once), readlane broadcast of (col,val) -> all x-row addresses known
//      upfront (no edge->x dependent chain). x-loads pipelined 8-deep ping-pong
//      (up to 16 in flight). val lives in SGPRs.
__global__ __launch_bounds__(256) void gather_rows_bf16(
    const unsigned short* __restrict__ xb, const float* __restrict__ h0,
    const int* __restrict__ row_start, const i32x2* __restrict__ edges,
    float* __restrict__ support, const float* __restrict__ alpha_p, int N) {
  int gid = blockIdx.x * 256 + threadIdx.x;
  int r = gid >> 6;
  if (r >= N) return;
  int lane = threadIdx.x & 63;
  float alpha = *alpha_p;
  int s = row_start[r], e = row_start[r + 1];

  const unsigned short* xbl = xb + lane * 4;  // per-lane column base

  f32x4 acc0 = (f32x4){0.f, 0.f, 0.f, 0.f};
  f32x4 acc1 = (f32x4){0.f, 0.f, 0.f, 0.f};

#define GRP_LOAD(XV, VV, JB)                                             \
  {                                                                      \
    _Pragma("unroll")                                                    \
    for (int k = 0; k < 8; ++k) {                                        \
      int col = __builtin_amdgcn_readlane(med.x, (JB) + k);              \
      VV[k] = __int_as_float(__builtin_amdgcn_readlane(med.y, (JB) + k)); \
      XV[k] = *(const u16x4*)(xbl + (size_t)col * F);                    \
    }                                                                    \
  }

#define GRP_FMA(XV, VV)                                                  \
  {                                                                      \
    _Pragma("unroll")                                                    \
    for (int k = 0; k < 8; ++k) {                                        \
      f32x4& A = (k & 1) ? acc1 : acc0;                                  \
      A.x += VV[k] * bf2f(XV[k][0]);                                     \
      A.y += VV[k] * bf2f(XV[k][1]);                                     \
      A.z += VV[k] * bf2f(XV[k][2]);                                     \
      A.w += VV[k] * bf2f(XV[k][3]);                                     \
    }                                                                    \
  }

  while (s < e) {
    int cnt = e - s;
    if (cnt > 64) cnt = 64;

    i32x2 med;
    if (lane < cnt) {
      med = edges[s + lane];
    } else {
      med.x = 0; med.y = 0;
    }

    u16x4 xA[8], xB[8];
    float vA[8], vB[8];

    int jb = 0;
    GRP_LOAD(xA, vA, 0);
    while (true) {
      int jn = jb + 8;
      if (jn < cnt) GRP_LOAD(xB, vB, jn);
      GRP_FMA(xA, vA);
      jb = jn;
      if (jb >= cnt) break;
      jn = jb + 8;
      if (jn < cnt) GRP_LOAD(xA, vA, jn);
      GRP_FMA(xB, vB);
      jb = jn;
      if (jb >= cnt) break;
    }
    s += cnt;
  }
#undef GRP_LOAD
#undef GRP_FMA

  f32x4 acc = acc0 + acc1;
  f32x4 b = __builtin_nontemporal_load((const f32x4*)(h0 + (size_t)r * F) + lane);
  float om = 1.0f - alpha;
  f32x4 o = om * acc + alpha * b;
  *((f32x4*)(support + (size_t)r * F) + lane) = o;
}

// ---- gather (fp32 x) fallback if ws can't hold xb ----
__global__ __launch_bounds__(256) void gather_rows_f32(
    const float* __restrict__ x, const float* __restrict__ h0,
    const int* __restrict__ row_start, const i32x2* __restrict__ edges,
    float* __restrict__ support, const float* __restrict__ alpha_p, int N) {
  int gid = blockIdx.x * 256 + threadIdx.x;
  int r = gid >> 6;
  if (r >= N) return;
  int lane = threadIdx.x & 63;
  float alpha = *alpha_p;
  int s = row_start[r], e = row_start[r + 1];
  f32x4 acc = (f32x4){0.f, 0.f, 0.f, 0.f};
  if (s < e) {
    i32x2 ed = __builtin_nontemporal_load(&edges[s]);
    f32x4 xv = *((const f32x4*)(x + (size_t)ed.x * F) + lane);
    for (int j = s; j < e; ++j) {
      i32x2 cur = ed;
      f32x4 xc = xv;
      if (j + 1 < e) {
        ed = __builtin_nontemporal_load(&edges[j + 1]);
        xv = *((const f32x4*)(x + (size_t)ed.x * F) + lane);
      }
      float v = __int_as_float(cur.y);
      acc += v * xc;
    }
  }
  f32x4 b = __builtin_nontemporal_load((const f32x4*)(h0 + (size_t)r * F) + lane);
  float om = 1.0f - alpha;
  f32x4 o = om * acc + alpha * b;
  *((f32x4*)(support + (size_t)r * F) + lane) = o;
}

// ---- GEMM + epilogue: out = theta*(support@W) + (1-theta)*support ----
// support and out alias (in-place): tile fully staged to LDS before writes.
__global__ __launch_bounds__(256) void gemm_epilogue(
    const float* support, const unsigned short* __restrict__ Wt, float* out,
    const float* __restrict__ lamda_p, const int* __restrict__ l_p, int N) {
  __shared__ unsigned short sup[64][264];  // +8 pad: 2-way bank alias (free)

  const float theta = logf(*lamda_p / (float)(*l_p) + 1.0f);
  const float one_m_t = 1.0f - theta;

  const int m0 = blockIdx.x * 64;
  const int t = threadIdx.x;

#pragma unroll
  for (int i = 0; i < 16; ++i) {
    int f = t + i * 256;
    int row = f >> 6, c4 = f & 63;
    int g_row = m0 + row;
    f32x4 a = (f32x4){0.f, 0.f, 0.f, 0.f};
    if (g_row < N)
      a = __builtin_nontemporal_load((const f32x4*)(support + (size_t)g_row * F) + c4);
    unsigned short* p = &sup[row][c4 << 2];
    p[0] = f2bf(a.x); p[1] = f2bf(a.y); p[2] = f2bf(a.z); p[3] = f2bf(a.w);
  }
  __syncthreads();

  const int wave = t >> 6, lane = t & 63;
  const int quad = lane >> 4, lcol = lane & 15;
  const int mrow = wave * 16;

  f32x4 acc[16];
#pragma unroll
  for (int n = 0; n < 16; ++n) acc[n] = (f32x4){0.f, 0.f, 0.f, 0.f};

#pragma unroll
  for (int k = 0; k < 8; ++k) {
    short8 afrag = *(const short8*)&sup[mrow + lcol][k * 32 + quad * 8];
#pragma unroll
    for (int n = 0; n < 16; ++n) {
      short8 bfrag = *(const short8*)&Wt[(size_t)(n * 16 + lcol) * F + k * 32 + quad * 8];
      acc[n] = __builtin_amdgcn_mfma_f32_16x16x32_bf16(afrag, bfrag, acc[n], 0, 0, 0);
    }
  }

#pragma unroll
  for (int n = 0; n < 16; ++n) {
#pragma unroll
    for (int r = 0; r < 4; ++r) {
      int lrow = mrow + quad * 4 + r;
      int col = n * 16 + lcol;
      int g_row = m0 + lrow;
      if (g_row < N) {
        float s = bf2f(sup[lrow][col]);
        __builtin_nontemporal_store(theta * acc[n][r] + one_m_t * s,
                                    &out[(size_t)g_row * F + col]);
      }
    }
  }
}

extern "C" void kernel_launch(void* const* d_in, const int* in_sizes, int n_in,
                              void* d_out, int out_size, void* d_ws, size_t ws_size,
                              hipStream_t stream) {
  const float* x     = (const float*)d_in[0];
  const int*   rows  = (const int*)d_in[1];
  const int*   cols  = (const int*)d_in[2];
  const float* vals  = (const float*)d_in[3];
  const float* h0    = (const float*)d_in[4];
  const float* W     = (const float*)d_in[5];
  const float* lamda = (const float*)d_in[6];
  const float* alpha = (const float*)d_in[7];
  const int*   lp    = (const int*)d_in[8];

  const int E = in_sizes[1];
  const int N = in_sizes[0] / F;
  const int NF = N * F;
  const int NB = (N + BKT_ROWS - 1) >> BKT_SHIFT;

  // ---- workspace layout (256B aligned regions) ----
  size_t off = 0;
  auto take = [&](size_t bytes) { size_t o = off; off += (bytes + 255) & ~(size_t)255; return o; };
  char* ws = (char*)d_ws;
  unsigned short* Wt  = (unsigned short*)(ws + take((size_t)F * F * 2));
  int* counts    = (int*)(ws + take((size_t)N * 4));
  int* row_start = (int*)(ws + take((size_t)(N + 1) * 4));
  int* fill_ptr  = (int*)(ws + take((size_t)N * 4));
  int* blk       = (int*)(ws + take(4096));
  int* bcur      = (int*)(ws + take(4096));
  i32x2* edges   = (i32x2*)(ws + take((size_t)E * 8));
  unsigned short* xb = (unsigned short*)(ws + take((size_t)NF * 2));
  const int use_bf16 = (off <= ws_size);

  float* out = (float*)d_out;

  // bucket sort usable? (col must fit 20 bits; out buffer big enough as scratch)
  const int use_sort = (N <= (1 << 20)) && (NB <= NB_MAX) &&
                       ((size_t)E * 8 <= (size_t)out_size);

  hipMemsetAsync(counts, 0, (size_t)N * sizeof(int), stream);

  int nxb = use_bf16 ? (NF + 2047) / 2048 : 0;
  prep<<<256 + nxb, 256, 0, stream>>>(W, Wt, x, xb, NF, use_bf16);

  int eb = (E + 255) / 256;
  int nb = (N + 255) / 256;  // must be <= 512 for scan2 (N=100000 -> 391)

  hist_rows<<<eb, 256, 0, stream>>>(rows, counts, E);
  scan1<<<nb, 256, 0, stream>>>(counts, row_start, blk, N);
  scan2<<<1, 512, 0, stream>>>(blk, nb);
  scan3<<<nb, 256, 0, stream>>>(counts, row_start, blk, fill_ptr, bcur, N);

  if (use_sort) {
    i32x2* etmp = (i32x2*)out;  // output buffer as binning scratch (free until gather)
    bin_edges<<<(E + BIN_CHUNK - 1) / BIN_CHUNK, 512, 0, stream>>>(
        rows, cols, vals, bcur, etmp, E, NB);
    sort_bucket<<<NB, 512, 0, stream>>>(etmp, row_start, fill_ptr, edges, N);
  } else {
    fill_csr<<<eb, 256, 0, stream>>>(rows, cols, vals, fill_ptr, (int2*)edges, E);
  }

  int gather_blocks = (N * 64 + 255) / 256;
  if (use_bf16) {
    gather_rows_bf16<<<gather_blocks, 256, 0, stream>>>(xb, h0, row_start, edges,
                                                        out, alpha, N);
  } else {
    gather_rows_f32<<<gather_blocks, 256, 0, stream>>>(x, h0, row_start, edges,
                                                       out, alpha, N);
  }

  gemm_epilogue<<<(N + 63) / 64, 256, 0, stream>>>(out, Wt, out, lamda, lp, N);
}

// Round 4
// 711.614 us; speedup vs baseline: 1.6691x; 1.1705x over previous
//
#include <hip/hip_runtime.h>
#include <math.h>

#define F 256

#define BKT_SHIFT 7
#define BKT_ROWS 128
#define BKT_CAP 8192   // LDS-sorted bucket capacity (64 KB)
#define NB_MAX 1024
#define BIN_CHUNK 8192

typedef __attribute__((ext_vector_type(8))) short short8;
typedef __attribute__((ext_vector_type(4))) float f32x4;
typedef __attribute__((ext_vector_type(2))) int i32x2;
typedef __attribute__((ext_vector_type(4))) unsigned short u16x4;
typedef __attribute__((ext_vector_type(8))) unsigned short u16x8;

__device__ __forceinline__ unsigned short f2bf(float f) {
  union { float f; unsigned u; } v; v.f = f;
  unsigned r = (v.u + 0x7fffu + ((v.u >> 16) & 1u)) >> 16;
  return (unsigned short)r;
}
__device__ __forceinline__ float bf2f(unsigned short h) {
  union { unsigned u; float f; } v; v.u = ((unsigned)h) << 16;
  return v.f;
}

// ---- prep: blocks [0,256): W[k][n] fp32 -> Wt[n][k] bf16.
//            blocks [256,..): x fp32 -> xb bf16 (8 elems/thread, NT reads).
__global__ void prep(const float* __restrict__ W, unsigned short* __restrict__ Wt,
                     const float* __restrict__ x, unsigned short* __restrict__ xb,
                     int NF, int do_xb) {
  if (blockIdx.x < 256) {
    int idx = blockIdx.x * 256 + threadIdx.x;
    int k = idx >> 8, n = idx & 255;
    Wt[n * F + k] = f2bf(W[k * F + n]);
    return;
  }
  if (!do_xb) return;
  int i0 = (blockIdx.x - 256) * 2048 + threadIdx.x * 8;
  if (i0 + 8 <= NF) {
    f32x4 a = __builtin_nontemporal_load((const f32x4*)(x + i0));
    f32x4 b = __builtin_nontemporal_load((const f32x4*)(x + i0 + 4));
    u16x8 o;
    o[0] = f2bf(a.x); o[1] = f2bf(a.y); o[2] = f2bf(a.z); o[3] = f2bf(a.w);
    o[4] = f2bf(b.x); o[5] = f2bf(b.y); o[6] = f2bf(b.z); o[7] = f2bf(b.w);
    *(u16x8*)(xb + i0) = o;
  } else {
    for (int i = i0; i < NF; ++i) xb[i] = f2bf(x[i]);
  }
}

// ========================= fallback CSR path =========================
__global__ void hist_rows(const int* __restrict__ rows, int* counts, int E) {
  int e = blockIdx.x * 256 + threadIdx.x;
  if (e < E) atomicAdd(&counts[__builtin_nontemporal_load(&rows[e])], 1);
}

__global__ void scan1(const int* __restrict__ counts, int* row_start, int* blk, int N) {
  __shared__ int tmp[256];
  int t = threadIdx.x;
  int i = blockIdx.x * 256 + t;
  int v = (i < N) ? counts[i] : 0;
  tmp[t] = v;
  __syncthreads();
#pragma unroll
  for (int off = 1; off < 256; off <<= 1) {
    int a = (t >= off) ? tmp[t - off] : 0;
    __syncthreads();
    tmp[t] += a;
    __syncthreads();
  }
  if (i < N) row_start[i] = tmp[t] - v;
  if (t == 255) blk[blockIdx.x] = tmp[255];
}

__global__ void scan2(int* blk, int NB) {
  __shared__ int tmp[512];
  int t = threadIdx.x;
  int v = (t < NB) ? blk[t] : 0;
  tmp[t] = v;
  __syncthreads();
#pragma unroll
  for (int off = 1; off < 512; off <<= 1) {
    int a = (t >= off) ? tmp[t - off] : 0;
    __syncthreads();
    tmp[t] += a;
    __syncthreads();
  }
  if (t < NB) blk[t] = tmp[t] - v;
}

__global__ void scan3(const int* __restrict__ counts, int* row_start,
                      const int* __restrict__ blk, int* fill_ptr, int N) {
  int i = blockIdx.x * 256 + threadIdx.x;
  if (i >= N) return;
  int rs = row_start[i] + blk[i >> 8];
  row_start[i] = rs;
  fill_ptr[i] = rs;
  if (i == N - 1) row_start[N] = rs + counts[i];
}

__global__ void fill_csr(const int* __restrict__ rows, const int* __restrict__ cols,
                         const float* __restrict__ vals, int* fill_ptr,
                         int2* __restrict__ edges, int E) {
  int e = blockIdx.x * 256 + threadIdx.x;
  if (e >= E) return;
  int r = __builtin_nontemporal_load(&rows[e]);
  int c = __builtin_nontemporal_load(&cols[e]);
  float v = __builtin_nontemporal_load(&vals[e]);
  int pos = atomicAdd(&fill_ptr[r], 1);
  edges[pos] = make_int2(c, __float_as_int(v));
}

// ========================= bucket CSR path =========================
// pass 0: block-aggregated bucket counts (one atomic per block,bucket).
__global__ __launch_bounds__(512) void bin_count(
    const int* __restrict__ rows, int* __restrict__ bucket_counts, int E, int NB) {
  __shared__ unsigned hist[NB_MAX];
  const int tid = threadIdx.x;
  const int e0 = blockIdx.x * BIN_CHUNK;
  for (int b = tid; b < NB; b += 512) hist[b] = 0;
  __syncthreads();
#pragma unroll
  for (int k = 0; k < BIN_CHUNK / 512; ++k) {
    int e = e0 + k * 512 + tid;
    if (e < E) {
      unsigned b = (unsigned)__builtin_nontemporal_load(&rows[e]) >> BKT_SHIFT;
      atomicAdd(&hist[b], 1u);
    }
  }
  __syncthreads();
  for (int b = tid; b < NB; b += 512)
    if (hist[b]) atomicAdd(&bucket_counts[b], (int)hist[b]);
}

// pass 1: exact bucket bases (exclusive scan, 1 block). Also row_start[N]=E.
__global__ __launch_bounds__(1024) void scan_buckets(
    const int* __restrict__ bucket_counts, int* __restrict__ bbase,
    int* __restrict__ bcur, int* __restrict__ row_start, int NB, int N, int E) {
  __shared__ int tmp[1024];
  int t = threadIdx.x;
  int v = (t < NB) ? bucket_counts[t] : 0;
  tmp[t] = v;
  __syncthreads();
#pragma unroll
  for (int off = 1; off < 1024; off <<= 1) {
    int a = (t >= off) ? tmp[t - off] : 0;
    __syncthreads();
    tmp[t] += a;
    __syncthreads();
  }
  if (t < NB) {
    int ex = tmp[t] - v;
    bbase[t] = ex;
    bcur[t] = ex;
  }
  if (t == 0) {
    bbase[NB] = E;
    row_start[N] = E;
  }
}

// pass 2: binning scatter into exact per-bucket regions.
// Packs (col | row_local<<20, val). Writes land in dense per-bucket runs.
__global__ __launch_bounds__(512) void bin_edges(
    const int* __restrict__ rows, const int* __restrict__ cols,
    const float* __restrict__ vals, int* __restrict__ bcur,
    i32x2* __restrict__ etmp, int E, int NB) {
  __shared__ unsigned hist[NB_MAX];
  __shared__ unsigned base[NB_MAX];
  const int tid = threadIdx.x;
  const int e0 = blockIdx.x * BIN_CHUNK;

  for (int b = tid; b < NB; b += 512) hist[b] = 0;
  __syncthreads();
#pragma unroll
  for (int k = 0; k < BIN_CHUNK / 512; ++k) {
    int e = e0 + k * 512 + tid;
    if (e < E) {
      unsigned b = (unsigned)__builtin_nontemporal_load(&rows[e]) >> BKT_SHIFT;
      atomicAdd(&hist[b], 1u);
    }
  }
  __syncthreads();
  for (int b = tid; b < NB; b += 512) {
    unsigned c = hist[b];
    base[b] = c ? (unsigned)atomicAdd(&bcur[b], (int)c) : 0u;
    hist[b] = 0;
  }
  __syncthreads();
#pragma unroll
  for (int k = 0; k < BIN_CHUNK / 512; ++k) {
    int e = e0 + k * 512 + tid;
    if (e < E) {
      int r = rows[e];
      unsigned b = (unsigned)r >> BKT_SHIFT;
      unsigned idx = atomicAdd(&hist[b], 1u);
      int pos = (int)(base[b] + idx);
      int c = cols[e];
      float v = vals[e];
      etmp[pos] = (i32x2){c | ((r & (BKT_ROWS - 1)) << 20), __float_as_int(v)};
    }
  }
}

// pass 3: per-bucket CSR finish. LDS hist -> scan -> writes row_start ->
// stable LDS scatter -> coalesced write. Strips row bits. Handles cnt>CAP
// via direct global scatter (correct for any input, just slower).
__global__ __launch_bounds__(512) void sort_bucket(
    const i32x2* __restrict__ etmp, const int* __restrict__ bbase,
    i32x2* __restrict__ edges, int* __restrict__ row_start, int N) {
  __shared__ int cur[BKT_ROWS];
  __shared__ int pre[BKT_ROWS];
  __shared__ i32x2 sorted[BKT_CAP];
  const int b = blockIdx.x;
  const int r0 = b << BKT_SHIFT;
  int nrows = N - r0; if (nrows > BKT_ROWS) nrows = BKT_ROWS;
  const int seg0 = bbase[b];
  const int cnt = bbase[b + 1] - seg0;
  const int tid = threadIdx.x;

  if (tid < BKT_ROWS) cur[tid] = 0;
  __syncthreads();
  for (int i = tid; i < cnt; i += 512) {
    i32x2 w = etmp[seg0 + i];
    atomicAdd(&cur[(w.x >> 20) & (BKT_ROWS - 1)], 1);
  }
  __syncthreads();
  int myc = (tid < BKT_ROWS) ? cur[tid] : 0;
  __syncthreads();
  for (int off = 1; off < BKT_ROWS; off <<= 1) {
    int a = 0;
    if (tid < BKT_ROWS && tid >= off) a = cur[tid - off];
    __syncthreads();
    if (tid < BKT_ROWS) cur[tid] += a;
    __syncthreads();
  }
  if (tid < BKT_ROWS) {
    int ex = cur[tid] - myc;   // exclusive prefix within bucket
    pre[tid] = ex;
    cur[tid] = ex;             // running cursor for scatter
    if (tid < nrows) row_start[r0 + tid] = seg0 + ex;
  }
  __syncthreads();

  if (cnt <= BKT_CAP) {
    for (int i = tid; i < cnt; i += 512) {
      i32x2 w = etmp[seg0 + i];
      int rl = (w.x >> 20) & (BKT_ROWS - 1);
      int idx = atomicAdd(&cur[rl], 1);
      sorted[idx] = (i32x2){w.x & 0xFFFFF, w.y};
    }
    __syncthreads();
    for (int i = tid; i < cnt; i += 512)
      edges[seg0 + i] = sorted[i];
  } else {
    for (int i = tid; i < cnt; i += 512) {
      i32x2 w = etmp[seg0 + i];
      int rl = (w.x >> 20) & (BKT_ROWS - 1);
      int idx = atomicAdd(&cur[rl], 1);
      edges[seg0 + idx] = (i32x2){w.x & 0xFFFFF, w.y};
    }
  }
}

// ---- gather (bf16 x): one wave per row. Wave-wide bulk edge load (64 edges),
// readlane broadcast -> all x addresses known upfront. 64-edge chunk fully
// unrolled as 16-deep ping-pong: up to 32 x-loads in flight.
__global__ __launch_bounds__(256) void gather_rows_bf16(
    const unsigned short* __restrict__ xb, const float* __restrict__ h0,
    const int* __restrict__ row_start, const i32x2* __restrict__ edges,
    float* __restrict__ support, const float* __restrict__ alpha_p, int N) {
  int gid = blockIdx.x * 256 + threadIdx.x;
  int r = gid >> 6;
  if (r >= N) return;
  int lane = threadIdx.x & 63;
  float alpha = *alpha_p;
  int s = row_start[r], e = row_start[r + 1];

  const unsigned short* xbl = xb + lane * 4;  // per-lane column base

  f32x4 acc0 = (f32x4){0.f, 0.f, 0.f, 0.f};
  f32x4 acc1 = (f32x4){0.f, 0.f, 0.f, 0.f};

#define GRP_LOAD16(XV, VV, JB)                                            \
  {                                                                       \
    _Pragma("unroll")                                                     \
    for (int k = 0; k < 16; ++k) {                                        \
      int col = __builtin_amdgcn_readlane(med.x, (JB) + k);               \
      VV[k] = __int_as_float(__builtin_amdgcn_readlane(med.y, (JB) + k)); \
      XV[k] = *(const u16x4*)(xbl + (size_t)col * F);                     \
    }                                                                     \
  }

#define GRP_FMA16(XV, VV)                                                 \
  {                                                                       \
    _Pragma("unroll")                                                     \
    for (int k = 0; k < 16; ++k) {                                        \
      f32x4& A = (k & 1) ? acc1 : acc0;                                   \
      A.x += VV[k] * bf2f(XV[k][0]);                                      \
      A.y += VV[k] * bf2f(XV[k][1]);                                      \
      A.z += VV[k] * bf2f(XV[k][2]);                                      \
      A.w += VV[k] * bf2f(XV[k][3]);                                      \
    }                                                                     \
  }

  while (s < e) {
    int cnt = e - s;
    if (cnt > 64) cnt = 64;

    i32x2 med;
    if (lane < cnt) {
      med = edges[s + lane];
    } else {
      med.x = 0; med.y = 0;  // pad: reads x row 0 with val 0 -> contributes 0
    }

    u16x4 xA[16], xB[16];
    float vA[16], vB[16];

    GRP_LOAD16(xA, vA, 0);
    if (cnt > 16) GRP_LOAD16(xB, vB, 16);
    GRP_FMA16(xA, vA);
    if (cnt > 16) {
      if (cnt > 32) GRP_LOAD16(xA, vA, 32);
      GRP_FMA16(xB, vB);
      if (cnt > 32) {
        if (cnt > 48) GRP_LOAD16(xB, vB, 48);
        GRP_FMA16(xA, vA);
        if (cnt > 48) GRP_FMA16(xB, vB);
      }
    }
    s += cnt;
  }
#undef GRP_LOAD16
#undef GRP_FMA16

  f32x4 acc = acc0 + acc1;
  f32x4 b = __builtin_nontemporal_load((const f32x4*)(h0 + (size_t)r * F) + lane);
  float om = 1.0f - alpha;
  f32x4 o = om * acc + alpha * b;
  *((f32x4*)(support + (size_t)r * F) + lane) = o;
}

// ---- gather (fp32 x) fallback if ws can't hold xb ----
__global__ __launch_bounds__(256) void gather_rows_f32(
    const float* __restrict__ x, const float* __restrict__ h0,
    const int* __restrict__ row_start, const i32x2* __restrict__ edges,
    float* __restrict__ support, const float* __restrict__ alpha_p, int N) {
  int gid = blockIdx.x * 256 + threadIdx.x;
  int r = gid >> 6;
  if (r >= N) return;
  int lane = threadIdx.x & 63;
  float alpha = *alpha_p;
  int s = row_start[r], e = row_start[r + 1];
  f32x4 acc = (f32x4){0.f, 0.f, 0.f, 0.f};
  if (s < e) {
    i32x2 ed = __builtin_nontemporal_load(&edges[s]);
    f32x4 xv = *((const f32x4*)(x + (size_t)ed.x * F) + lane);
    for (int j = s; j < e; ++j) {
      i32x2 cur = ed;
      f32x4 xc = xv;
      if (j + 1 < e) {
        ed = __builtin_nontemporal_load(&edges[j + 1]);
        xv = *((const f32x4*)(x + (size_t)ed.x * F) + lane);
      }
      float v = __int_as_float(cur.y);
      acc += v * xc;
    }
  }
  f32x4 b = __builtin_nontemporal_load((const f32x4*)(h0 + (size_t)r * F) + lane);
  float om = 1.0f - alpha;
  f32x4 o = om * acc + alpha * b;
  *((f32x4*)(support + (size_t)r * F) + lane) = o;
}

// ---- GEMM + epilogue: out = theta*(support@W) + (1-theta)*support ----
// support and out alias (in-place): tile fully staged to LDS before writes.
__global__ __launch_bounds__(256) void gemm_epilogue(
    const float* support, const unsigned short* __restrict__ Wt, float* out,
    const float* __restrict__ lamda_p, const int* __restrict__ l_p, int N) {
  __shared__ unsigned short sup[64][264];  // +8 pad: 2-way bank alias (free)

  const float theta = logf(*lamda_p / (float)(*l_p) + 1.0f);
  const float one_m_t = 1.0f - theta;

  const int m0 = blockIdx.x * 64;
  const int t = threadIdx.x;

#pragma unroll
  for (int i = 0; i < 16; ++i) {
    int f = t + i * 256;
    int row = f >> 6, c4 = f & 63;
    int g_row = m0 + row;
    f32x4 a = (f32x4){0.f, 0.f, 0.f, 0.f};
    if (g_row < N)
      a = __builtin_nontemporal_load((const f32x4*)(support + (size_t)g_row * F) + c4);
    unsigned short* p = &sup[row][c4 << 2];
    p[0] = f2bf(a.x); p[1] = f2bf(a.y); p[2] = f2bf(a.z); p[3] = f2bf(a.w);
  }
  __syncthreads();

  const int wave = t >> 6, lane = t & 63;
  const int quad = lane >> 4, lcol = lane & 15;
  const int mrow = wave * 16;

  f32x4 acc[16];
#pragma unroll
  for (int n = 0; n < 16; ++n) acc[n] = (f32x4){0.f, 0.f, 0.f, 0.f};

#pragma unroll
  for (int k = 0; k < 8; ++k) {
    short8 afrag = *(const short8*)&sup[mrow + lcol][k * 32 + quad * 8];
#pragma unroll
    for (int n = 0; n < 16; ++n) {
      short8 bfrag = *(const short8*)&Wt[(size_t)(n * 16 + lcol) * F + k * 32 + quad * 8];
      acc[n] = __builtin_amdgcn_mfma_f32_16x16x32_bf16(afrag, bfrag, acc[n], 0, 0, 0);
    }
  }

#pragma unroll
  for (int n = 0; n < 16; ++n) {
#pragma unroll
    for (int r = 0; r < 4; ++r) {
      int lrow = mrow + quad * 4 + r;
      int col = n * 16 + lcol;
      int g_row = m0 + lrow;
      if (g_row < N) {
        float s = bf2f(sup[lrow][col]);
        __builtin_nontemporal_store(theta * acc[n][r] + one_m_t * s,
                                    &out[(size_t)g_row * F + col]);
      }
    }
  }
}

extern "C" void kernel_launch(void* const* d_in, const int* in_sizes, int n_in,
                              void* d_out, int out_size, void* d_ws, size_t ws_size,
                              hipStream_t stream) {
  const float* x     = (const float*)d_in[0];
  const int*   rows  = (const int*)d_in[1];
  const int*   cols  = (const int*)d_in[2];
  const float* vals  = (const float*)d_in[3];
  const float* h0    = (const float*)d_in[4];
  const float* W     = (const float*)d_in[5];
  const float* lamda = (const float*)d_in[6];
  const float* alpha = (const float*)d_in[7];
  const int*   lp    = (const int*)d_in[8];

  const int E = in_sizes[1];
  const int N = in_sizes[0] / F;
  const int NF = N * F;
  const int NB = (N + BKT_ROWS - 1) >> BKT_SHIFT;

  // ---- workspace layout (256B aligned regions) ----
  size_t off = 0;
  auto take = [&](size_t bytes) { size_t o = off; off += (bytes + 255) & ~(size_t)255; return o; };
  char* ws = (char*)d_ws;
  unsigned short* Wt  = (unsigned short*)(ws + take((size_t)F * F * 2));
  int* counts    = (int*)(ws + take((size_t)N * 4));         // fallback only
  int* row_start = (int*)(ws + take((size_t)(N + 1) * 4));
  int* fill_ptr  = (int*)(ws + take((size_t)N * 4));         // fallback only
  int* blk       = (int*)(ws + take(4096));                  // fallback only
  int* bucket_counts = (int*)(ws + take((size_t)NB_MAX * 4));
  int* bbase     = (int*)(ws + take((size_t)(NB_MAX + 1) * 4));
  int* bcur      = (int*)(ws + take((size_t)NB_MAX * 4));
  i32x2* edges   = (i32x2*)(ws + take((size_t)E * 8));
  unsigned short* xb = (unsigned short*)(ws + take((size_t)NF * 2));
  const int use_bf16 = (off <= ws_size);

  float* out = (float*)d_out;

  // bucket sort usable? (col fits 20 bits; scan_buckets width; out as scratch)
  const int use_sort = (N <= (1 << 20)) && (NB <= NB_MAX) &&
                       ((size_t)E * 8 <= (size_t)out_size);

  int nxb = use_bf16 ? (NF + 2047) / 2048 : 0;
  prep<<<256 + nxb, 256, 0, stream>>>(W, Wt, x, xb, NF, use_bf16);

  int eb = (E + 255) / 256;
  int nb = (N + 255) / 256;  // must be <= 512 for scan2 (N=100000 -> 391)
  int bchunks = (E + BIN_CHUNK - 1) / BIN_CHUNK;

  if (use_sort) {
    i32x2* etmp = (i32x2*)out;  // output buffer as binning scratch (free until gather)
    hipMemsetAsync(bucket_counts, 0, (size_t)NB * sizeof(int), stream);
    bin_count<<<bchunks, 512, 0, stream>>>(rows, bucket_counts, E, NB);
    scan_buckets<<<1, 1024, 0, stream>>>(bucket_counts, bbase, bcur, row_start,
                                         NB, N, E);
    bin_edges<<<bchunks, 512, 0, stream>>>(rows, cols, vals, bcur, etmp, E, NB);
    sort_bucket<<<NB, 512, 0, stream>>>(etmp, bbase, edges, row_start, N);
  } else {
    hipMemsetAsync(counts, 0, (size_t)N * sizeof(int), stream);
    hist_rows<<<eb, 256, 0, stream>>>(rows, counts, E);
    scan1<<<nb, 256, 0, stream>>>(counts, row_start, blk, N);
    scan2<<<1, 512, 0, stream>>>(blk, nb);
    scan3<<<nb, 256, 0, stream>>>(counts, row_start, blk, fill_ptr, N);
    fill_csr<<<eb, 256, 0, stream>>>(rows, cols, vals, fill_ptr, (int2*)edges, E);
  }

  int gather_blocks = (N * 64 + 255) / 256;
  if (use_bf16) {
    gather_rows_bf16<<<gather_blocks, 256, 0, stream>>>(xb, h0, row_start, edges,
                                                        out, alpha, N);
  } else {
    gather_rows_f32<<<gather_blocks, 256, 0, stream>>>(x, h0, row_start, edges,
                                                       out, alpha, N);
  }

  gemm_epilogue<<<(N + 63) / 64, 256, 0, stream>>>(out, Wt, out, lamda, lp, N);
}